// Round 6
// baseline (74.816 us; speedup 1.0000x reference)
//
#include <hip/hip_runtime.h>
#include <hip/hip_bf16.h>
#include <math.h>

#define BSZ 512      // batch
#define FDIM 512     // features
#define NK 32        // num_kernels
#define DD 16        // dim_per_kernel
#define NDIM (NK*DD) // 512
#define OUTW (FDIM + NK)  // 544

typedef __attribute__((ext_vector_type(8))) short short8;   // bf16x8 frag
typedef __attribute__((ext_vector_type(4))) float float4v;  // C/D frag

static __device__ __forceinline__ short f2bf(float f) {
  return (short)__builtin_bit_cast(unsigned short, __float2bfloat16(f));
}

// ---------------------------------------------------------------------------
// Kernel 1: m = x @ T via bf16 MFMA + out-prep.
// R5 lesson: this kernel was ~24us regardless of VALU/MFMA structure --
// latency-serialized cold misses (poison fill sweeps L2/L3 every iteration;
// compiler sinks loads next to uses, so few misses in flight). Fixes:
//  (a) touch phase: 4 independent copy-shaped float4 reads/thread covering
//      all of x+T (slice = blockIdx>>3, so each 8-block group sweeps the
//      full 2MB -> warms every XCD's L2 at full MLP). Sink via inline asm
//      at kernel END so no early waitcnt.
//  (b) all 40 GEMM loads batched into register arrays BEFORE any cvt/MFMA
//      -> 40 outstanding VMEM per wave even with naive scheduling.
// grid 1024 = 32rg x 32cg (16x16 tile), 256 thr = 4 waves (wave = K-chunk
// of 128 = 4x mfma 16x16x32_bf16); LDS K-reduce; __launch_bounds__(256,4)
// caps VGPR at 128 so 4 blocks/CU (16 waves/CU) stay resident.
// Layouts (HW-verified m89): A[m=lane&15][k=8q+i], C/D col=lane&15,
// row=4q+reg; A and B share the k-map so internal permutation cancels.
// ---------------------------------------------------------------------------
__global__ __launch_bounds__(256, 4) void k_gemm(
    const float* __restrict__ x, const float* __restrict__ T,
    float* __restrict__ m, float* __restrict__ out) {
  const int t  = threadIdx.x;
  const int b  = blockIdx.x;
  const int rg = b >> 5, cg = b & 31;
  const int r0 = rg * 16, c0 = cg * 16;
  const int lane = t & 63;
  const int w    = __builtin_amdgcn_readfirstlane(t >> 6);  // K-chunk 0..3
  const int mi   = lane & 15;   // A row / B col / C col
  const int q    = lane >> 4;   // quad -> k = 8q + i

  // ---- phase 0: L2-warming touch of x and T (copy-shaped, max MLP) ----
  // x,T are each 65536 float4; 128 slices x 512 float4; 2 float4/thread/arr.
  const int slice = b >> 3;  // 0..127
  const float4 w0 = ((const float4*)x)[(size_t)slice * 512 + t];
  const float4 w1 = ((const float4*)x)[(size_t)slice * 512 + t + 256];
  const float4 w2 = ((const float4*)T)[(size_t)slice * 512 + t];
  const float4 w3 = ((const float4*)T)[(size_t)slice * 512 + t + 256];
  const float sink = w0.x + w1.y + w2.z + w3.w;

  // ---- phase 1: issue ALL 40 fragment loads before any use ----
  const float* __restrict__ xa = x + (size_t)(r0 + mi) * FDIM + 128 * w + 8 * q;
  const float* __restrict__ tb = T + (size_t)(128 * w + 8 * q) * NDIM + c0 + mi;
  float4 A[8];
  float  Bv[32];
#pragma unroll
  for (int j = 0; j < 4; ++j) {
    A[2 * j]     = *(const float4*)(xa + 32 * j);
    A[2 * j + 1] = *(const float4*)(xa + 32 * j + 4);
  }
#pragma unroll
  for (int j = 0; j < 4; ++j)
#pragma unroll
    for (int i = 0; i < 8; ++i)
      Bv[8 * j + i] = tb[(size_t)(32 * j + i) * NDIM];

  // ---- phase 2: convert + 4 MFMAs ----
  float4v acc = {0.f, 0.f, 0.f, 0.f};
#pragma unroll
  for (int j = 0; j < 4; ++j) {
    short8 af, bf;
    af[0] = f2bf(A[2*j].x);   af[1] = f2bf(A[2*j].y);
    af[2] = f2bf(A[2*j].z);   af[3] = f2bf(A[2*j].w);
    af[4] = f2bf(A[2*j+1].x); af[5] = f2bf(A[2*j+1].y);
    af[6] = f2bf(A[2*j+1].z); af[7] = f2bf(A[2*j+1].w);
#pragma unroll
    for (int i = 0; i < 8; ++i) bf[i] = f2bf(Bv[8 * j + i]);
    acc = __builtin_amdgcn_mfma_f32_16x16x32_bf16(af, bf, acc, 0, 0, 0);
  }

  // ---- K-reduce the 4 waves through LDS; C/D row=4q+reg, col=mi ----
  __shared__ float red[4][16][16];
#pragma unroll
  for (int r = 0; r < 4; ++r) red[w][q * 4 + r][mi] = acc[r];
  __syncthreads();
  {
    const int orow = t >> 4, ocol = t & 15;
    const float s = red[0][orow][ocol] + red[1][orow][ocol] +
                    red[2][orow][ocol] + red[3][orow][ocol];
    m[(size_t)(r0 + orow) * NDIM + c0 + ocol] = s;
  }

  // ---- out-prep: g in [0, 262144) over the grid ----
  const int g = b * 256 + t;
  if (g < 65536) {  // copy x -> out[:, :512]: 512 rows x 128 float4 (L2-warm)
    const int orow = g >> 7, c4 = g & 127;
    *(float4*)(out + (size_t)orow * OUTW + c4 * 4) =
        *(const float4*)(x + (size_t)orow * FDIM + c4 * 4);
  } else if (g < 65536 + 16384) {  // zero feats cols (out poisoned pre-launch)
    const int idx = g - 65536;
    const int orow = idx >> 5, kk = idx & 31;
    out[(size_t)orow * OUTW + FDIM + kk] = 0.f;
  }

  // keep the touch loads alive without forcing an early waitcnt
  asm volatile("" : : "v"(sink));
}

// ---------------------------------------------------------------------------
// Kernel 2 (unchanged, ~5-7us): feats[i,k] +=
// sum_j exp(-sum_d |m[i,k,d]-m[j,k,d]|). B-slice staged in LDS, hot loop is
// uniform LDS broadcast + VALU; 1024 blocks x 256 thr = 16 waves/CU.
// ---------------------------------------------------------------------------
__global__ __launch_bounds__(256) void k_dist(
    const float* __restrict__ m, float* __restrict__ out) {
  __shared__ float Bs[128 * DD];  // 8 KB
  __shared__ float red[256];
  const int t   = threadIdx.x;
  const int bid = blockIdx.x;
  const int ig  = bid >> 7;         // 0..7
  const int k   = (bid >> 2) & 31;  // 0..31
  const int jq  = bid & 3;          // j quarter
  const int lane = t & 63;
  const int i    = ig * 64 + lane;

  const float4* ap = (const float4*)(m + (size_t)i * NDIM + k * DD);
  const float4 A0 = ap[0], A1 = ap[1], A2 = ap[2], A3 = ap[3];

  const float* mb = m + (size_t)(jq * 128) * NDIM + k * DD;
#pragma unroll
  for (int qq = 0; qq < 2; ++qq) {
    const int idx = qq * 256 + t;        // 0..511
    const int jrow = idx >> 2, part = idx & 3;
    *(float4*)&Bs[jrow * DD + part * 4] =
        *(const float4*)(mb + (size_t)jrow * NDIM + part * 4);
  }
  __syncthreads();

  float a[DD];
  a[0]=A0.x; a[1]=A0.y; a[2]=A0.z;  a[3]=A0.w;
  a[4]=A1.x; a[5]=A1.y; a[6]=A1.z;  a[7]=A1.w;
  a[8]=A2.x; a[9]=A2.y; a[10]=A2.z; a[11]=A2.w;
  a[12]=A3.x;a[13]=A3.y;a[14]=A3.z; a[15]=A3.w;

  const int w = __builtin_amdgcn_readfirstlane(t >> 6);  // wave 0..3
  const int jbase = w * 32;
  float f = 0.f;
#pragma unroll 4
  for (int j = 0; j < 32; ++j) {
    const float4* bp = (const float4*)&Bs[(jbase + j) * DD];  // uniform
    const float4 b0 = bp[0], b1 = bp[1], b2 = bp[2], b3 = bp[3];
    float d =
        fabsf(a[0]  - b0.x) + fabsf(a[1]  - b0.y) +
        fabsf(a[2]  - b0.z) + fabsf(a[3]  - b0.w) +
        fabsf(a[4]  - b1.x) + fabsf(a[5]  - b1.y) +
        fabsf(a[6]  - b1.z) + fabsf(a[7]  - b1.w) +
        fabsf(a[8]  - b2.x) + fabsf(a[9]  - b2.y) +
        fabsf(a[10] - b2.z) + fabsf(a[11] - b2.w) +
        fabsf(a[12] - b3.x) + fabsf(a[13] - b3.y) +
        fabsf(a[14] - b3.z) + fabsf(a[15] - b3.w);
    f += __expf(-d);
  }

  red[t] = f;
  __syncthreads();
  if (t < 64) {
    const float s = red[t] + red[t + 64] + red[t + 128] + red[t + 192];
    atomicAdd(out + (size_t)(ig * 64 + t) * OUTW + FDIM + k, s);
  }
}

extern "C" void kernel_launch(void* const* d_in, const int* in_sizes, int n_in,
                              void* d_out, int out_size, void* d_ws,
                              size_t ws_size, hipStream_t stream) {
  (void)in_sizes; (void)n_in; (void)out_size; (void)ws_size;
  const float* x = (const float*)d_in[0];
  const float* T = (const float*)d_in[1];
  float* out = (float*)d_out;
  float* m   = (float*)d_ws;  // [512][512] fp32, 1 MB

  hipLaunchKernelGGL(k_gemm, dim3(1024), dim3(256), 0, stream, x, T, m, out);
  hipLaunchKernelGGL(k_dist, dim3(1024), dim3(256), 0, stream, m, out);
}